// Round 7
// baseline (486.686 us; speedup 1.0000x reference)
//
#include <hip/hip_runtime.h>
#include <hip/hip_fp16.h>

#define N    8192
#define FIN  256
#define FOUT 128
#define BN   64

typedef _Float16 half8 __attribute__((ext_vector_type(8)));
typedef _Float16 half4v __attribute__((ext_vector_type(4)));
typedef float floatx4 __attribute__((ext_vector_type(4)));

// ---------------------------------------------------------------------------
// Mask-prep v2: Msk2[g][i] (u64), bit l <-> adj[i][g*64 + l].
// One wave per row; 128 coalesced 256-B loads + ballots per row.
// ---------------------------------------------------------------------------
__global__ __launch_bounds__(256)
void maskprep_kernel(const int* __restrict__ adj,
                     unsigned long long* __restrict__ Msk2)
{
    const int wave = threadIdx.x >> 6;
    const int lane = threadIdx.x & 63;
    const int row  = blockIdx.x * 4 + wave;
    const int* base = adj + (size_t)row * N;
    for (int g = 0; g < 128; g++) {
        int v = base[g * 64 + lane];
        unsigned long long b = __ballot(v != 0);
        if (lane == 0) Msk2[(size_t)g * N + row] = b;
    }
}

// ---------------------------------------------------------------------------
// W-prep: frag-major fp16 W for coalesced MFMA B-loads.
// ---------------------------------------------------------------------------
__global__ __launch_bounds__(256)
void wprep_kernel(const float* __restrict__ W0,
                  const float* __restrict__ W1,
                  const float* __restrict__ W2,
                  _Float16* __restrict__ Wf)
{
    int idx  = blockIdx.x * 256 + threadIdx.x;   // 0..12287
    int lane = idx & 63;
    int frag = idx >> 6;
    int w    = frag >> 6;
    int f    = frag & 63;
    int nt   = f >> 3, kc = f & 7;
    int quad = lane >> 4, lo16 = lane & 15;
    const float* Wp = w == 0 ? W0 : (w == 1 ? W1 : W2);
    half8 v;
#pragma unroll
    for (int jj = 0; jj < 8; jj++)
        v[jj] = (_Float16)Wp[(size_t)(kc * 32 + quad * 8 + jj) * FOUT + nt * 16 + lo16];
    *(half8*)&Wf[(size_t)idx * 8] = v;
}

// ---------------------------------------------------------------------------
// H = fp16(inp@W), H2 = fp16(inp@W2), H3T = fp16((inp@W3)^T). Barrier-free.
// ---------------------------------------------------------------------------
__global__ __launch_bounds__(256, 2)
void gemm3_kernel(const float* __restrict__ inp,
                  const _Float16* __restrict__ Wf,
                  _Float16* __restrict__ H,
                  _Float16* __restrict__ H2,
                  _Float16* __restrict__ H3T)
{
    const int which = blockIdx.z;
    const int c0    = blockIdx.y * 64;
    const _Float16* Wfw = Wf + (size_t)which * 64 * 64 * 8;
    const int r0 = blockIdx.x * 64;
    const int tid  = threadIdx.x;
    const int wave = tid >> 6;
    const int lane = tid & 63;
    const int lo16 = lane & 15;
    const int quad = lane >> 4;
    const int r = r0 + wave * 16 + lo16;

    half8 a[8];
#pragma unroll
    for (int kc = 0; kc < 8; kc++) {
        const float* p = &inp[(size_t)r * FIN + kc * 32 + quad * 8];
        float4 v0 = *(const float4*)p;
        float4 v1 = *(const float4*)(p + 4);
        a[kc][0] = (_Float16)v0.x; a[kc][1] = (_Float16)v0.y;
        a[kc][2] = (_Float16)v0.z; a[kc][3] = (_Float16)v0.w;
        a[kc][4] = (_Float16)v1.x; a[kc][5] = (_Float16)v1.y;
        a[kc][6] = (_Float16)v1.z; a[kc][7] = (_Float16)v1.w;
    }

    floatx4 acc[4];
#pragma unroll
    for (int i = 0; i < 4; i++) acc[i] = (floatx4){0.f, 0.f, 0.f, 0.f};

#pragma unroll
    for (int kc = 0; kc < 8; kc++)
#pragma unroll
        for (int nt = 0; nt < 4; nt++) {
            int ntg = (c0 >> 4) + nt;
            half8 b = *(const half8*)&Wfw[(((size_t)ntg * 8 + kc) * 64 + lane) * 8];
            acc[nt] = __builtin_amdgcn_mfma_f32_16x16x32_f16(a[kc], b, acc[nt], 0, 0, 0);
        }

    const int arow = wave * 16 + quad * 4;
    if (which < 2) {
        _Float16* outp = which == 0 ? H : H2;
#pragma unroll
        for (int nt = 0; nt < 4; nt++)
#pragma unroll
            for (int rr = 0; rr < 4; rr++)
                outp[(size_t)(r0 + arow + rr) * FOUT + c0 + nt * 16 + lo16] = (_Float16)acc[nt][rr];
    } else {
#pragma unroll
        for (int nt = 0; nt < 4; nt++) {
            half4v v;
#pragma unroll
            for (int rr = 0; rr < 4; rr++) v[rr] = (_Float16)acc[nt][rr];
            *(half4v*)&H3T[(size_t)(c0 + nt * 16 + lo16) * N + r0 + arow] = v;
        }
    }
}

// ---------------------------------------------------------------------------
// Repack K with the sigma j-permutation baked in:
// Kf[jb][c(2)][ntj(2)][kc(4)][lane][8] =
//   H2[jb*64 + c*32 + 8*(lo16>>2) + 4*ntj + (lo16&3)][kc*32 + quad*8 + jj]
// With this layout, S^T rows land so each lane's 16 P values are exactly
// the PV B-fragment j-set {8*quad .. 8*quad+7} per 32-chunk (no shuffles).
// ---------------------------------------------------------------------------
__global__ __launch_bounds__(256)
void repackK_kernel(const _Float16* __restrict__ H2, _Float16* __restrict__ Kf)
{
    int idx  = blockIdx.x * 256 + threadIdx.x;
    int lane = idx & 63;
    int frag = idx >> 6;
    int jb = frag >> 4, f = frag & 15;
    int c = f >> 3, ntj = (f >> 2) & 1, kc = f & 3;
    int quad = lane >> 4, lo16 = lane & 15;
    int srcrow = jb * 64 + c * 32 + (lo16 >> 2) * 8 + ntj * 4 + (lo16 & 3);
    half8 v = *(const half8*)&H2[(size_t)srcrow * FOUT + kc * 32 + quad * 8];
    *(half8*)&Kf[(size_t)idx * 8] = v;
}

// ---------------------------------------------------------------------------
// Repack V^T into frag-major (unchanged layout; now used as the PV A-operand).
// Vf[jb][ntf(8)][kcj(2)][lane][8] = H3T[ntf*16+lo16][jb*64+kcj*32+quad*8+jj]
// ---------------------------------------------------------------------------
__global__ __launch_bounds__(256)
void repackV_kernel(const _Float16* __restrict__ H3T, _Float16* __restrict__ Vf)
{
    int idx  = blockIdx.x * 256 + threadIdx.x;
    int lane = idx & 63;
    int frag = idx >> 6;
    int jb = frag >> 4, f = frag & 15, nt = f >> 1, kc = f & 1;
    int quad = lane >> 4, lo16 = lane & 15;
    half8 v = *(const half8*)&H3T[(size_t)(nt * 16 + lo16) * N + jb * 64 + kc * 32 + quad * 8];
    *(half8*)&Vf[(size_t)idx * 8] = v;
}

// ---------------------------------------------------------------------------
// Flash attention v3: S^T formulation. 32 i-rows per wave (BM=128/block),
// double-buffered KV LDS, 1 barrier/iter, no P LDS round-trip, 2-step
// softmax butterflies, coalesced u64 mask loads. O^T accumulation; epilogue
// writes f-major OpartT.
// ---------------------------------------------------------------------------
template<int JS>
__global__ __launch_bounds__(256, 2)
void attn_kernel(const _Float16* __restrict__ Hq,   // [N][128]
                 const _Float16* __restrict__ Kf,   // permuted frag-major
                 const _Float16* __restrict__ Vf,   // frag-major
                 const unsigned long long* __restrict__ Msk2, // [128][N]
                 float* __restrict__ OpartT,        // [JS][FOUT][N]
                 float* __restrict__ mpart,         // [JS][N]
                 float* __restrict__ lpart)         // [JS][N]
{
    __shared__ _Float16 KV[2][16384];   // [buf][16 K frags | 16 V frags]

    const int tid  = threadIdx.x;
    const int wave = tid >> 6;
    const int lane = tid & 63;
    const int lo16 = lane & 15;
    const int quad = lane >> 4;
    const int bid  = blockIdx.x;
    const int js   = bid & (JS - 1);      // XCD affinity
    const int ib   = bid / JS;
    const int i0   = ib * 128;
    const int iw   = i0 + wave * 32;
    const int jbeg = js * (N / JS);
    const int NIT  = (N / JS) / BN;

    // Q as B-operand fragments for 2 i-subtiles
    half8 q[2][4];
#pragma unroll
    for (int isub = 0; isub < 2; isub++)
#pragma unroll
        for (int kc = 0; kc < 4; kc++)
            q[isub][kc] = *(const half8*)&Hq[(size_t)(iw + isub * 16 + lo16) * FOUT + kc * 32 + quad * 8];

    floatx4 O[8][2];
#pragma unroll
    for (int nt = 0; nt < 8; nt++)
#pragma unroll
        for (int s = 0; s < 2; s++) O[nt][s] = (floatx4){0.f, 0.f, 0.f, 0.f};
    float m_s[2] = {-1e12f, -1e12f}, l_s[2] = {0.f, 0.f};

    // prologue: stage tile 0 into buf 0
    {
        const int jb0 = jbeg >> 6;
        const _Float16* gk = Kf + (size_t)jb0 * 8192;
        const _Float16* gv = Vf + (size_t)jb0 * 8192;
#pragma unroll
        for (int r = 0; r < 4; r++) {
            int off = (r * 256 + tid) * 8;
            *(half8*)&KV[0][off]        = *(const half8*)&gk[off];
            *(half8*)&KV[0][8192 + off] = *(const half8*)&gv[off];
        }
        __syncthreads();
    }

    int cur = 0;
    for (int it = 0; it < NIT; it++) {
        const int j0 = jbeg + it * BN;

        // prefetch next tile into regs (in flight during compute)
        half8 st[8];
        if (it + 1 < NIT) {
            const int jbn = (j0 + BN) >> 6;
            const _Float16* gk = Kf + (size_t)jbn * 8192;
            const _Float16* gv = Vf + (size_t)jbn * 8192;
#pragma unroll
            for (int r = 0; r < 4; r++) {
                int off = (r * 256 + tid) * 8;
                st[r]     = *(const half8*)&gk[off];
                st[r + 4] = *(const half8*)&gv[off];
            }
        }
        // mask words: coalesced, one u64 per i
        unsigned long long mw[2];
        mw[0] = Msk2[(size_t)(j0 >> 6) * N + iw + lo16];
        mw[1] = Msk2[(size_t)(j0 >> 6) * N + iw + 16 + lo16];

        const _Float16* kb = &KV[cur][0];
        const _Float16* vb = &KV[cur][8192];

        // S^T = K Q^T : C-row = j (sigma-permuted), C-col = i
        floatx4 S[2][2][2];   // [c][ntj][isub]
#pragma unroll
        for (int c = 0; c < 2; c++)
#pragma unroll
            for (int ntj = 0; ntj < 2; ntj++) {
                S[c][ntj][0] = (floatx4){0.f, 0.f, 0.f, 0.f};
                S[c][ntj][1] = (floatx4){0.f, 0.f, 0.f, 0.f};
#pragma unroll
                for (int kc = 0; kc < 4; kc++) {
                    half8 kf = *(const half8*)&kb[(((c * 2 + ntj) * 4 + kc) * 64 + lane) * 8];
                    S[c][ntj][0] = __builtin_amdgcn_mfma_f32_16x16x32_f16(kf, q[0][kc], S[c][ntj][0], 0, 0, 0);
                    S[c][ntj][1] = __builtin_amdgcn_mfma_f32_16x16x32_f16(kf, q[1][kc], S[c][ntj][1], 0, 0, 0);
                }
            }

        // LeakyReLU (this lane holds j = c*32 + 8*quad + 4*ntj + r, i = isub*16+lo16)
        float ev[2][2][2][4];
#pragma unroll
        for (int c = 0; c < 2; c++)
#pragma unroll
            for (int ntj = 0; ntj < 2; ntj++)
#pragma unroll
                for (int s = 0; s < 2; s++)
#pragma unroll
                    for (int r = 0; r < 4; r++) {
                        float e = S[c][ntj][s][r];
                        ev[c][ntj][s][r] = e > 0.f ? e : 0.2f * e;
                    }

        // unmasked running max per i: lane-local 16, then 2-step quad butterfly
        float alpha[2];
#pragma unroll
        for (int s = 0; s < 2; s++) {
            float mx = ev[0][0][s][0];
#pragma unroll
            for (int c = 0; c < 2; c++)
#pragma unroll
                for (int ntj = 0; ntj < 2; ntj++)
#pragma unroll
                    for (int r = 0; r < 4; r++)
                        mx = fmaxf(mx, ev[c][ntj][s][r]);
            mx = fmaxf(mx, __shfl_xor(mx, 16));
            mx = fmaxf(mx, __shfl_xor(mx, 32));
            float mn = fmaxf(m_s[s], mx);
            alpha[s] = __expf(m_s[s] - mn);
            m_s[s] = mn;
        }

        // P = mask ? exp(ev - m) : 0 ; pack directly into PV B-fragments
        half8 pb[2][2];       // [isub][c], element jj = 4*ntj + r
        float sum[2] = {0.f, 0.f};
#pragma unroll
        for (int s = 0; s < 2; s++) {
            unsigned long long mq = mw[s] >> (quad * 8);
#pragma unroll
            for (int c = 0; c < 2; c++)
#pragma unroll
                for (int ntj = 0; ntj < 2; ntj++)
#pragma unroll
                    for (int r = 0; r < 4; r++) {
                        bool bit = (mq >> (c * 32 + ntj * 4 + r)) & 1ull;
                        float p = bit ? __expf(ev[c][ntj][s][r] - m_s[s]) : 0.f;
                        sum[s] += p;
                        pb[s][c][ntj * 4 + r] = (_Float16)p;
                    }
            sum[s] += __shfl_xor(sum[s], 16);
            sum[s] += __shfl_xor(sum[s], 32);
            l_s[s] = l_s[s] * alpha[s] + sum[s];
#pragma unroll
            for (int nt = 0; nt < 8; nt++)
#pragma unroll
                for (int r = 0; r < 4; r++)
                    O[nt][s][r] *= alpha[s];
        }

        // O^T += V^T P^T  (A = V^T frag from LDS, B = pb in regs)
#pragma unroll
        for (int c = 0; c < 2; c++)
#pragma unroll
            for (int nt = 0; nt < 8; nt++) {
                half8 vf = *(const half8*)&vb[((nt * 2 + c) * 64 + lane) * 8];
                O[nt][0] = __builtin_amdgcn_mfma_f32_16x16x32_f16(vf, pb[0][c], O[nt][0], 0, 0, 0);
                O[nt][1] = __builtin_amdgcn_mfma_f32_16x16x32_f16(vf, pb[1][c], O[nt][1], 0, 0, 0);
            }

        // commit prefetched tile; one barrier per iter
        if (it + 1 < NIT) {
            const int nxt = cur ^ 1;
#pragma unroll
            for (int r = 0; r < 4; r++) {
                int off = (r * 256 + tid) * 8;
                *(half8*)&KV[nxt][off]        = st[r];
                *(half8*)&KV[nxt][8192 + off] = st[r + 4];
            }
        }
        __syncthreads();
        cur ^= 1;
    }

    // epilogue: O^T[f][i] -> OpartT[js][f][i] (unnormalized) + (m,l)
#pragma unroll
    for (int nt = 0; nt < 8; nt++)
#pragma unroll
        for (int s = 0; s < 2; s++)
#pragma unroll
            for (int r = 0; r < 4; r++) {
                int f = nt * 16 + quad * 4 + r;
                int i = iw + s * 16 + lo16;
                OpartT[((size_t)js * FOUT + f) * N + i] = O[nt][s][r];
            }
    if (quad == 0) {
#pragma unroll
        for (int s = 0; s < 2; s++) {
            mpart[js * N + iw + s * 16 + lo16] = m_s[s];
            lpart[js * N + iw + s * 16 + lo16] = l_s[s];
        }
    }
}

// ---------------------------------------------------------------------------
// Combine v2: f-major partials. thread -> (f, 4 consecutive i).
// ---------------------------------------------------------------------------
template<int JS>
__global__ __launch_bounds__(256)
void combine_kernel(const float* __restrict__ OpartT,
                    const float* __restrict__ mpart,
                    const float* __restrict__ lpart,
                    float* __restrict__ out)
{
    int idx = blockIdx.x * 256 + threadIdx.x;   // 128 f x 2048 i-groups
    int f  = idx >> 11;
    int i4 = (idx & 2047) << 2;

    float4 M = {-3e38f, -3e38f, -3e38f, -3e38f};
    float4 m[JS];
#pragma unroll
    for (int s = 0; s < JS; s++) {
        m[s] = *(const float4*)&mpart[s * N + i4];
        M.x = fmaxf(M.x, m[s].x); M.y = fmaxf(M.y, m[s].y);
        M.z = fmaxf(M.z, m[s].z); M.w = fmaxf(M.w, m[s].w);
    }
    float4 L = {0.f, 0.f, 0.f, 0.f};
    float4 w[JS];
#pragma unroll
    for (int s = 0; s < JS; s++) {
        float4 l = *(const float4*)&lpart[s * N + i4];
        w[s].x = __expf(m[s].x - M.x); w[s].y = __expf(m[s].y - M.y);
        w[s].z = __expf(m[s].z - M.z); w[s].w = __expf(m[s].w - M.w);
        L.x += l.x * w[s].x; L.y += l.y * w[s].y;
        L.z += l.z * w[s].z; L.w += l.w * w[s].w;
    }
    float4 o = {0.f, 0.f, 0.f, 0.f};
#pragma unroll
    for (int s = 0; s < JS; s++) {
        float4 v = *(const float4*)&OpartT[((size_t)s * FOUT + f) * N + i4];
        o.x += w[s].x * v.x; o.y += w[s].y * v.y;
        o.z += w[s].z * v.z; o.w += w[s].w * v.w;
    }
    float r0 = o.x / L.x, r1 = o.y / L.y, r2 = o.z / L.z, r3 = o.w / L.w;
    out[(size_t)(i4 + 0) * FOUT + f] = r0 > 0.f ? r0 : __expf(r0) - 1.f;
    out[(size_t)(i4 + 1) * FOUT + f] = r1 > 0.f ? r1 : __expf(r1) - 1.f;
    out[(size_t)(i4 + 2) * FOUT + f] = r2 > 0.f ? r2 : __expf(r2) - 1.f;
    out[(size_t)(i4 + 3) * FOUT + f] = r3 > 0.f ? r3 : __expf(r3) - 1.f;
}

// ---------------------------------------------------------------------------
extern "C" void kernel_launch(void* const* d_in, const int* in_sizes, int n_in,
                              void* d_out, int out_size, void* d_ws, size_t ws_size,
                              hipStream_t stream) {
    const float* inp = (const float*)d_in[0];
    const int*   adj = (const int*)d_in[1];
    const float* W0  = (const float*)d_in[2];
    const float* W1  = (const float*)d_in[3];
    const float* W2  = (const float*)d_in[4];
    float* out = (float*)d_out;

    constexpr int JS = 8;
    char* ws = (char*)d_ws;
    _Float16* H    = (_Float16*)(ws);                          // 2 MB
    _Float16* H2   = (_Float16*)(ws + (2u << 20));             // 2 MB
    _Float16* H3T  = (_Float16*)(ws + (4u << 20));             // 2 MB
    _Float16* Wf   = (_Float16*)(ws + (6u << 20));             // 192 KB
    unsigned long long* Msk2 = (unsigned long long*)(ws + (7u << 20)); // 8 MB
    _Float16* Kf   = (_Float16*)(ws + (15u << 20));            // 2 MB
    _Float16* Vf   = (_Float16*)(ws + (17u << 20));            // 2 MB
    float* OpartT  = (float*)(ws + (19u << 20));               // 32 MB
    float* mpart   = (float*)(ws + (51u << 20));               // 256 KB
    float* lpart   = (float*)(ws + (51u << 20) + (size_t)JS * N * sizeof(float));

    maskprep_kernel<<<N / 4, 256, 0, stream>>>(adj, Msk2);
    wprep_kernel<<<48, 256, 0, stream>>>(W0, W1, W2, Wf);
    gemm3_kernel<<<dim3(N / 64, 2, 3), 256, 0, stream>>>(inp, Wf, H, H2, H3T);
    repackK_kernel<<<512, 256, 0, stream>>>(H2, Kf);
    repackV_kernel<<<512, 256, 0, stream>>>(H3T, Vf);
    attn_kernel<JS><<<(N / 128) * JS, 256, 0, stream>>>(H, Kf, Vf, Msk2, OpartT, mpart, lpart);
    combine_kernel<JS><<<(FOUT * (N / 4)) / 256, 256, 0, stream>>>(OpartT, mpart, lpart, out);
}

// Round 8
// 432.621 us; speedup vs baseline: 1.1250x; 1.1250x over previous
//
#include <hip/hip_runtime.h>
#include <hip/hip_fp16.h>

#define N    8192
#define FIN  256
#define FOUT 128
#define BN   64

typedef _Float16 half8 __attribute__((ext_vector_type(8)));
typedef _Float16 half4v __attribute__((ext_vector_type(4)));
typedef float floatx4 __attribute__((ext_vector_type(4)));

// ---------------------------------------------------------------------------
// W-prep: frag-major fp16 W for coalesced MFMA B-loads.
// ---------------------------------------------------------------------------
__global__ __launch_bounds__(256)
void wprep_kernel(const float* __restrict__ W0,
                  const float* __restrict__ W1,
                  const float* __restrict__ W2,
                  _Float16* __restrict__ Wf)
{
    int idx  = blockIdx.x * 256 + threadIdx.x;   // 0..12287
    int lane = idx & 63;
    int frag = idx >> 6;
    int w    = frag >> 6;
    int f    = frag & 63;
    int nt   = f >> 3, kc = f & 7;
    int quad = lane >> 4, lo16 = lane & 15;
    const float* Wp = w == 0 ? W0 : (w == 1 ? W1 : W2);
    half8 v;
#pragma unroll
    for (int jj = 0; jj < 8; jj++)
        v[jj] = (_Float16)Wp[(size_t)(kc * 32 + quad * 8 + jj) * FOUT + nt * 16 + lo16];
    *(half8*)&Wf[(size_t)idx * 8] = v;
}

// ---------------------------------------------------------------------------
// H = fp16(inp@W), H2 = fp16(inp@W2), H3T = fp16((inp@W3)^T). Barrier-free.
// ---------------------------------------------------------------------------
__global__ __launch_bounds__(256, 2)
void gemm3_kernel(const float* __restrict__ inp,
                  const _Float16* __restrict__ Wf,
                  _Float16* __restrict__ H,
                  _Float16* __restrict__ H2,
                  _Float16* __restrict__ H3T)
{
    const int which = blockIdx.z;
    const int c0    = blockIdx.y * 64;
    const _Float16* Wfw = Wf + (size_t)which * 64 * 64 * 8;
    const int r0 = blockIdx.x * 64;
    const int tid  = threadIdx.x;
    const int wave = tid >> 6;
    const int lane = tid & 63;
    const int lo16 = lane & 15;
    const int quad = lane >> 4;
    const int r = r0 + wave * 16 + lo16;

    half8 a[8];
#pragma unroll
    for (int kc = 0; kc < 8; kc++) {
        const float* p = &inp[(size_t)r * FIN + kc * 32 + quad * 8];
        float4 v0 = *(const float4*)p;
        float4 v1 = *(const float4*)(p + 4);
        a[kc][0] = (_Float16)v0.x; a[kc][1] = (_Float16)v0.y;
        a[kc][2] = (_Float16)v0.z; a[kc][3] = (_Float16)v0.w;
        a[kc][4] = (_Float16)v1.x; a[kc][5] = (_Float16)v1.y;
        a[kc][6] = (_Float16)v1.z; a[kc][7] = (_Float16)v1.w;
    }

    floatx4 acc[4];
#pragma unroll
    for (int i = 0; i < 4; i++) acc[i] = (floatx4){0.f, 0.f, 0.f, 0.f};

#pragma unroll
    for (int kc = 0; kc < 8; kc++)
#pragma unroll
        for (int nt = 0; nt < 4; nt++) {
            int ntg = (c0 >> 4) + nt;
            half8 b = *(const half8*)&Wfw[(((size_t)ntg * 8 + kc) * 64 + lane) * 8];
            acc[nt] = __builtin_amdgcn_mfma_f32_16x16x32_f16(a[kc], b, acc[nt], 0, 0, 0);
        }

    const int arow = wave * 16 + quad * 4;
    if (which < 2) {
        _Float16* outp = which == 0 ? H : H2;
#pragma unroll
        for (int nt = 0; nt < 4; nt++)
#pragma unroll
            for (int rr = 0; rr < 4; rr++)
                outp[(size_t)(r0 + arow + rr) * FOUT + c0 + nt * 16 + lo16] = (_Float16)acc[nt][rr];
    } else {
#pragma unroll
        for (int nt = 0; nt < 4; nt++) {
            half4v v;
#pragma unroll
            for (int rr = 0; rr < 4; rr++) v[rr] = (_Float16)acc[nt][rr];
            *(half4v*)&H3T[(size_t)(c0 + nt * 16 + lo16) * N + r0 + arow] = v;
        }
    }
}

// ---------------------------------------------------------------------------
// Repack K with the sigma j-permutation baked in (see R7 comment).
// ---------------------------------------------------------------------------
__global__ __launch_bounds__(256)
void repackK_kernel(const _Float16* __restrict__ H2, _Float16* __restrict__ Kf)
{
    int idx  = blockIdx.x * 256 + threadIdx.x;
    int lane = idx & 63;
    int frag = idx >> 6;
    int jb = frag >> 4, f = frag & 15;
    int c = f >> 3, ntj = (f >> 2) & 1, kc = f & 3;
    int quad = lane >> 4, lo16 = lane & 15;
    int srcrow = jb * 64 + c * 32 + (lo16 >> 2) * 8 + ntj * 4 + (lo16 & 3);
    half8 v = *(const half8*)&H2[(size_t)srcrow * FOUT + kc * 32 + quad * 8];
    *(half8*)&Kf[(size_t)idx * 8] = v;
}

// ---------------------------------------------------------------------------
// Repack V^T into frag-major (PV A-operand).
// ---------------------------------------------------------------------------
__global__ __launch_bounds__(256)
void repackV_kernel(const _Float16* __restrict__ H3T, _Float16* __restrict__ Vf)
{
    int idx  = blockIdx.x * 256 + threadIdx.x;
    int lane = idx & 63;
    int frag = idx >> 6;
    int jb = frag >> 4, f = frag & 15, nt = f >> 1, kc = f & 1;
    int quad = lane >> 4, lo16 = lane & 15;
    half8 v = *(const half8*)&H3T[(size_t)(nt * 16 + lo16) * N + jb * 64 + kc * 32 + quad * 8];
    *(half8*)&Vf[(size_t)idx * 8] = v;
}

// ---------------------------------------------------------------------------
// Flash attention v4: S^T formulation, 32 i-rows/wave, dbuf KV LDS,
// 1 barrier/iter. Adjacency folded in: coalesced 256-B adj row reads +
// in-wave __ballot -> per-i u64 masks (no separate maskprep pass).
// ---------------------------------------------------------------------------
template<int JS>
__global__ __launch_bounds__(256, 2)
void attn_kernel(const _Float16* __restrict__ Hq,   // [N][128]
                 const _Float16* __restrict__ Kf,   // permuted frag-major
                 const _Float16* __restrict__ Vf,   // frag-major
                 const int* __restrict__ adj,       // [N][N]
                 float* __restrict__ OpartT,        // [JS][FOUT][N]
                 float* __restrict__ mpart,         // [JS][N]
                 float* __restrict__ lpart)         // [JS][N]
{
    __shared__ _Float16 KV[2][16384];   // [buf][16 K frags | 16 V frags]

    const int tid  = threadIdx.x;
    const int wave = tid >> 6;
    const int lane = tid & 63;
    const int lo16 = lane & 15;
    const int quad = lane >> 4;
    const int bid  = blockIdx.x;
    const int js   = bid & (JS - 1);      // XCD affinity
    const int ib   = bid / JS;
    const int i0   = ib * 128;
    const int iw   = i0 + wave * 32;
    const int jbeg = js * (N / JS);
    const int NIT  = (N / JS) / BN;

    // Q as B-operand fragments for 2 i-subtiles
    half8 q[2][4];
#pragma unroll
    for (int isub = 0; isub < 2; isub++)
#pragma unroll
        for (int kc = 0; kc < 4; kc++)
            q[isub][kc] = *(const half8*)&Hq[(size_t)(iw + isub * 16 + lo16) * FOUT + kc * 32 + quad * 8];

    floatx4 O[8][2];
#pragma unroll
    for (int nt = 0; nt < 8; nt++)
#pragma unroll
        for (int s = 0; s < 2; s++) O[nt][s] = (floatx4){0.f, 0.f, 0.f, 0.f};
    float m_s[2] = {-1e12f, -1e12f}, l_s[2] = {0.f, 0.f};

    // prologue: stage tile 0 into buf 0
    {
        const int jb0 = jbeg >> 6;
        const _Float16* gk = Kf + (size_t)jb0 * 8192;
        const _Float16* gv = Vf + (size_t)jb0 * 8192;
#pragma unroll
        for (int r = 0; r < 4; r++) {
            int off = (r * 256 + tid) * 8;
            *(half8*)&KV[0][off]        = *(const half8*)&gk[off];
            *(half8*)&KV[0][8192 + off] = *(const half8*)&gv[off];
        }
        __syncthreads();
    }

    int cur = 0;
    for (int it = 0; it < NIT; it++) {
        const int j0 = jbeg + it * BN;

        // ---- adj row reads for this (i-block, j-window): 32 x 256B coalesced,
        //      issued first; consumed by ballots just before the P pass ----
        int av[32];
        {
            const int* ap = adj + (size_t)iw * N + j0 + lane;
#pragma unroll
            for (int x = 0; x < 32; x++) av[x] = ap[(size_t)x * N];
        }

        // prefetch next KV tile into regs (in flight during compute)
        half8 st[8];
        if (it + 1 < NIT) {
            const int jbn = (j0 + BN) >> 6;
            const _Float16* gk = Kf + (size_t)jbn * 8192;
            const _Float16* gv = Vf + (size_t)jbn * 8192;
#pragma unroll
            for (int r = 0; r < 4; r++) {
                int off = (r * 256 + tid) * 8;
                st[r]     = *(const half8*)&gk[off];
                st[r + 4] = *(const half8*)&gv[off];
            }
        }

        const _Float16* kb = &KV[cur][0];
        const _Float16* vb = &KV[cur][8192];

        // S^T = K Q^T : C-row = j (sigma-permuted), C-col = i
        floatx4 S[2][2][2];   // [c][ntj][isub]
#pragma unroll
        for (int c = 0; c < 2; c++)
#pragma unroll
            for (int ntj = 0; ntj < 2; ntj++) {
                S[c][ntj][0] = (floatx4){0.f, 0.f, 0.f, 0.f};
                S[c][ntj][1] = (floatx4){0.f, 0.f, 0.f, 0.f};
#pragma unroll
                for (int kc = 0; kc < 4; kc++) {
                    half8 kf = *(const half8*)&kb[(((c * 2 + ntj) * 4 + kc) * 64 + lane) * 8];
                    S[c][ntj][0] = __builtin_amdgcn_mfma_f32_16x16x32_f16(kf, q[0][kc], S[c][ntj][0], 0, 0, 0);
                    S[c][ntj][1] = __builtin_amdgcn_mfma_f32_16x16x32_f16(kf, q[1][kc], S[c][ntj][1], 0, 0, 0);
                }
            }

        // unmasked running max per i (LeakyReLU inline), 2-step butterfly
        float alpha[2];
#pragma unroll
        for (int s = 0; s < 2; s++) {
            float mx = -1e12f;
#pragma unroll
            for (int c = 0; c < 2; c++)
#pragma unroll
                for (int ntj = 0; ntj < 2; ntj++)
#pragma unroll
                    for (int r = 0; r < 4; r++) {
                        float e = S[c][ntj][s][r];
                        e = e > 0.f ? e : 0.2f * e;
                        mx = fmaxf(mx, e);
                    }
            mx = fmaxf(mx, __shfl_xor(mx, 16));
            mx = fmaxf(mx, __shfl_xor(mx, 32));
            float mn = fmaxf(m_s[s], mx);
            alpha[s] = __expf(m_s[s] - mn);
            m_s[s] = mn;
        }

        // ballots: bit l of b(x) = adj[iw+x][j0+l]; route to the lane owning i
        unsigned long long mw0 = 0, mw1 = 0;
#pragma unroll
        for (int x = 0; x < 16; x++) {
            unsigned long long b0 = __ballot(av[x] != 0);
            unsigned long long b1 = __ballot(av[x + 16] != 0);
            bool sel = (lo16 == x);
            mw0 = sel ? b0 : mw0;
            mw1 = sel ? b1 : mw1;
        }
        unsigned long long mw[2] = {mw0, mw1};

        // P = mask ? exp(leaky(S) - m) : 0 ; pack into PV B-fragments
        half8 pb[2][2];       // [isub][c], element jj = 4*ntj + r
        float sum[2] = {0.f, 0.f};
#pragma unroll
        for (int s = 0; s < 2; s++) {
            unsigned long long mq = mw[s] >> (quad * 8);
#pragma unroll
            for (int c = 0; c < 2; c++)
#pragma unroll
                for (int ntj = 0; ntj < 2; ntj++)
#pragma unroll
                    for (int r = 0; r < 4; r++) {
                        float e = S[c][ntj][s][r];
                        e = e > 0.f ? e : 0.2f * e;
                        bool bit = (mq >> (c * 32 + ntj * 4 + r)) & 1ull;
                        float p = bit ? __expf(e - m_s[s]) : 0.f;
                        sum[s] += p;
                        pb[s][c][ntj * 4 + r] = (_Float16)p;
                    }
            sum[s] += __shfl_xor(sum[s], 16);
            sum[s] += __shfl_xor(sum[s], 32);
            l_s[s] = l_s[s] * alpha[s] + sum[s];
#pragma unroll
            for (int nt = 0; nt < 8; nt++)
#pragma unroll
                for (int r = 0; r < 4; r++)
                    O[nt][s][r] *= alpha[s];
        }

        // O^T += V^T P^T  (A = V^T frag from LDS, B = pb in regs)
#pragma unroll
        for (int c = 0; c < 2; c++)
#pragma unroll
            for (int nt = 0; nt < 8; nt++) {
                half8 vf = *(const half8*)&vb[((nt * 2 + c) * 64 + lane) * 8];
                O[nt][0] = __builtin_amdgcn_mfma_f32_16x16x32_f16(vf, pb[0][c], O[nt][0], 0, 0, 0);
                O[nt][1] = __builtin_amdgcn_mfma_f32_16x16x32_f16(vf, pb[1][c], O[nt][1], 0, 0, 0);
            }

        // commit prefetched tile; one barrier per iter
        if (it + 1 < NIT) {
            const int nxt = cur ^ 1;
#pragma unroll
            for (int r = 0; r < 4; r++) {
                int off = (r * 256 + tid) * 8;
                *(half8*)&KV[nxt][off]        = st[r];
                *(half8*)&KV[nxt][8192 + off] = st[r + 4];
            }
        }
        __syncthreads();
        cur ^= 1;
    }

    // epilogue: O^T[f][i] -> OpartT[js][f][i] (unnormalized) + (m,l)
#pragma unroll
    for (int nt = 0; nt < 8; nt++)
#pragma unroll
        for (int s = 0; s < 2; s++)
#pragma unroll
            for (int r = 0; r < 4; r++) {
                int f = nt * 16 + quad * 4 + r;
                int i = iw + s * 16 + lo16;
                OpartT[((size_t)js * FOUT + f) * N + i] = O[nt][s][r];
            }
    if (quad == 0) {
#pragma unroll
        for (int s = 0; s < 2; s++) {
            mpart[js * N + iw + s * 16 + lo16] = m_s[s];
            lpart[js * N + iw + s * 16 + lo16] = l_s[s];
        }
    }
}

// ---------------------------------------------------------------------------
// Combine: f-major partials -> normalize -> ELU -> out[i][f].
// ---------------------------------------------------------------------------
template<int JS>
__global__ __launch_bounds__(256)
void combine_kernel(const float* __restrict__ OpartT,
                    const float* __restrict__ mpart,
                    const float* __restrict__ lpart,
                    float* __restrict__ out)
{
    int idx = blockIdx.x * 256 + threadIdx.x;   // 128 f x 2048 i-groups
    int f  = idx >> 11;
    int i4 = (idx & 2047) << 2;

    float4 M = {-3e38f, -3e38f, -3e38f, -3e38f};
    float4 m[JS];
#pragma unroll
    for (int s = 0; s < JS; s++) {
        m[s] = *(const float4*)&mpart[s * N + i4];
        M.x = fmaxf(M.x, m[s].x); M.y = fmaxf(M.y, m[s].y);
        M.z = fmaxf(M.z, m[s].z); M.w = fmaxf(M.w, m[s].w);
    }
    float4 L = {0.f, 0.f, 0.f, 0.f};
    float4 w[JS];
#pragma unroll
    for (int s = 0; s < JS; s++) {
        float4 l = *(const float4*)&lpart[s * N + i4];
        w[s].x = __expf(m[s].x - M.x); w[s].y = __expf(m[s].y - M.y);
        w[s].z = __expf(m[s].z - M.z); w[s].w = __expf(m[s].w - M.w);
        L.x += l.x * w[s].x; L.y += l.y * w[s].y;
        L.z += l.z * w[s].z; L.w += l.w * w[s].w;
    }
    float4 o = {0.f, 0.f, 0.f, 0.f};
#pragma unroll
    for (int s = 0; s < JS; s++) {
        float4 v = *(const float4*)&OpartT[((size_t)s * FOUT + f) * N + i4];
        o.x += w[s].x * v.x; o.y += w[s].y * v.y;
        o.z += w[s].z * v.z; o.w += w[s].w * v.w;
    }
    float r0 = o.x / L.x, r1 = o.y / L.y, r2 = o.z / L.z, r3 = o.w / L.w;
    out[(size_t)(i4 + 0) * FOUT + f] = r0 > 0.f ? r0 : __expf(r0) - 1.f;
    out[(size_t)(i4 + 1) * FOUT + f] = r1 > 0.f ? r1 : __expf(r1) - 1.f;
    out[(size_t)(i4 + 2) * FOUT + f] = r2 > 0.f ? r2 : __expf(r2) - 1.f;
    out[(size_t)(i4 + 3) * FOUT + f] = r3 > 0.f ? r3 : __expf(r3) - 1.f;
}

// ---------------------------------------------------------------------------
extern "C" void kernel_launch(void* const* d_in, const int* in_sizes, int n_in,
                              void* d_out, int out_size, void* d_ws, size_t ws_size,
                              hipStream_t stream) {
    const float* inp = (const float*)d_in[0];
    const int*   adj = (const int*)d_in[1];
    const float* W0  = (const float*)d_in[2];
    const float* W1  = (const float*)d_in[3];
    const float* W2  = (const float*)d_in[4];
    float* out = (float*)d_out;

    constexpr int JS = 8;
    char* ws = (char*)d_ws;
    _Float16* H    = (_Float16*)(ws);                          // 2 MB
    _Float16* H2   = (_Float16*)(ws + (2u << 20));             // 2 MB
    _Float16* H3T  = (_Float16*)(ws + (4u << 20));             // 2 MB
    _Float16* Wf   = (_Float16*)(ws + (6u << 20));             // 192 KB
    _Float16* Kf   = (_Float16*)(ws + (7u << 20));             // 2 MB
    _Float16* Vf   = (_Float16*)(ws + (9u << 20));             // 2 MB
    float* OpartT  = (float*)(ws + (11u << 20));               // 32 MB
    float* mpart   = (float*)(ws + (43u << 20));               // 256 KB
    float* lpart   = (float*)(ws + (43u << 20) + (size_t)JS * N * sizeof(float));

    wprep_kernel<<<48, 256, 0, stream>>>(W0, W1, W2, Wf);
    gemm3_kernel<<<dim3(N / 64, 2, 3), 256, 0, stream>>>(inp, Wf, H, H2, H3T);
    repackK_kernel<<<512, 256, 0, stream>>>(H2, Kf);
    repackV_kernel<<<512, 256, 0, stream>>>(H3T, Vf);
    attn_kernel<JS><<<(N / 128) * JS, 256, 0, stream>>>(H, Kf, Vf, adj, OpartT, mpart, lpart);
    combine_kernel<JS><<<(FOUT * (N / 4)) / 256, 256, 0, stream>>>(OpartT, mpart, lpart, out);
}

// Round 9
// 428.495 us; speedup vs baseline: 1.1358x; 1.0096x over previous
//
#include <hip/hip_runtime.h>
#include <hip/hip_fp16.h>

#define N    8192
#define FIN  256
#define FOUT 128
#define BN   64

typedef _Float16 half8 __attribute__((ext_vector_type(8)));
typedef _Float16 half4v __attribute__((ext_vector_type(4)));
typedef float floatx4 __attribute__((ext_vector_type(4)));

// ---------------------------------------------------------------------------
// W-prep: frag-major fp16 W for coalesced MFMA B-loads.
// ---------------------------------------------------------------------------
__global__ __launch_bounds__(256)
void wprep_kernel(const float* __restrict__ W0,
                  const float* __restrict__ W1,
                  const float* __restrict__ W2,
                  _Float16* __restrict__ Wf)
{
    int idx  = blockIdx.x * 256 + threadIdx.x;   // 0..12287
    int lane = idx & 63;
    int frag = idx >> 6;
    int w    = frag >> 6;
    int f    = frag & 63;
    int nt   = f >> 3, kc = f & 7;
    int quad = lane >> 4, lo16 = lane & 15;
    const float* Wp = w == 0 ? W0 : (w == 1 ? W1 : W2);
    half8 v;
#pragma unroll
    for (int jj = 0; jj < 8; jj++)
        v[jj] = (_Float16)Wp[(size_t)(kc * 32 + quad * 8 + jj) * FOUT + nt * 16 + lo16];
    *(half8*)&Wf[(size_t)idx * 8] = v;
}

// ---------------------------------------------------------------------------
// H = fp16(inp@W), H2 = fp16(inp@W2), H3T = fp16((inp@W3)^T). Barrier-free.
// ---------------------------------------------------------------------------
__global__ __launch_bounds__(256, 2)
void gemm3_kernel(const float* __restrict__ inp,
                  const _Float16* __restrict__ Wf,
                  _Float16* __restrict__ H,
                  _Float16* __restrict__ H2,
                  _Float16* __restrict__ H3T)
{
    const int which = blockIdx.z;
    const int c0    = blockIdx.y * 64;
    const _Float16* Wfw = Wf + (size_t)which * 64 * 64 * 8;
    const int r0 = blockIdx.x * 64;
    const int tid  = threadIdx.x;
    const int wave = tid >> 6;
    const int lane = tid & 63;
    const int lo16 = lane & 15;
    const int quad = lane >> 4;
    const int r = r0 + wave * 16 + lo16;

    half8 a[8];
#pragma unroll
    for (int kc = 0; kc < 8; kc++) {
        const float* p = &inp[(size_t)r * FIN + kc * 32 + quad * 8];
        float4 v0 = *(const float4*)p;
        float4 v1 = *(const float4*)(p + 4);
        a[kc][0] = (_Float16)v0.x; a[kc][1] = (_Float16)v0.y;
        a[kc][2] = (_Float16)v0.z; a[kc][3] = (_Float16)v0.w;
        a[kc][4] = (_Float16)v1.x; a[kc][5] = (_Float16)v1.y;
        a[kc][6] = (_Float16)v1.z; a[kc][7] = (_Float16)v1.w;
    }

    floatx4 acc[4];
#pragma unroll
    for (int i = 0; i < 4; i++) acc[i] = (floatx4){0.f, 0.f, 0.f, 0.f};

#pragma unroll
    for (int kc = 0; kc < 8; kc++)
#pragma unroll
        for (int nt = 0; nt < 4; nt++) {
            int ntg = (c0 >> 4) + nt;
            half8 b = *(const half8*)&Wfw[(((size_t)ntg * 8 + kc) * 64 + lane) * 8];
            acc[nt] = __builtin_amdgcn_mfma_f32_16x16x32_f16(a[kc], b, acc[nt], 0, 0, 0);
        }

    const int arow = wave * 16 + quad * 4;
    if (which < 2) {
        _Float16* outp = which == 0 ? H : H2;
#pragma unroll
        for (int nt = 0; nt < 4; nt++)
#pragma unroll
            for (int rr = 0; rr < 4; rr++)
                outp[(size_t)(r0 + arow + rr) * FOUT + c0 + nt * 16 + lo16] = (_Float16)acc[nt][rr];
    } else {
#pragma unroll
        for (int nt = 0; nt < 4; nt++) {
            half4v v;
#pragma unroll
            for (int rr = 0; rr < 4; rr++) v[rr] = (_Float16)acc[nt][rr];
            *(half4v*)&H3T[(size_t)(c0 + nt * 16 + lo16) * N + r0 + arow] = v;
        }
    }
}

// ---------------------------------------------------------------------------
// Repack K with the sigma j-permutation baked in (see R7 comment).
// ---------------------------------------------------------------------------
__global__ __launch_bounds__(256)
void repackK_kernel(const _Float16* __restrict__ H2, _Float16* __restrict__ Kf)
{
    int idx  = blockIdx.x * 256 + threadIdx.x;
    int lane = idx & 63;
    int frag = idx >> 6;
    int jb = frag >> 4, f = frag & 15;
    int c = f >> 3, ntj = (f >> 2) & 1, kc = f & 3;
    int quad = lane >> 4, lo16 = lane & 15;
    int srcrow = jb * 64 + c * 32 + (lo16 >> 2) * 8 + ntj * 4 + (lo16 & 3);
    half8 v = *(const half8*)&H2[(size_t)srcrow * FOUT + kc * 32 + quad * 8];
    *(half8*)&Kf[(size_t)idx * 8] = v;
}

// ---------------------------------------------------------------------------
// Repack V^T into frag-major (PV A-operand).
// ---------------------------------------------------------------------------
__global__ __launch_bounds__(256)
void repackV_kernel(const _Float16* __restrict__ H3T, _Float16* __restrict__ Vf)
{
    int idx  = blockIdx.x * 256 + threadIdx.x;
    int lane = idx & 63;
    int frag = idx >> 6;
    int jb = frag >> 4, f = frag & 15, nt = f >> 1, kc = f & 1;
    int quad = lane >> 4, lo16 = lane & 15;
    half8 v = *(const half8*)&H3T[(size_t)(nt * 16 + lo16) * N + jb * 64 + kc * 32 + quad * 8];
    *(half8*)&Vf[(size_t)idx * 8] = v;
}

// ---------------------------------------------------------------------------
// Flash attention v5: S^T formulation, 32 i-rows/wave, dbuf KV LDS,
// 1 barrier/iter. Adjacency folded in AND software-pipelined one full
// iteration ahead: ballot the previously-loaded window at iteration top
// (vmcnt slack = one whole iteration >> HBM latency), then issue the next
// window's 32 coalesced 256-B row loads.
// ---------------------------------------------------------------------------
template<int JS>
__global__ __launch_bounds__(256, 2)
void attn_kernel(const _Float16* __restrict__ Hq,   // [N][128]
                 const _Float16* __restrict__ Kf,   // permuted frag-major
                 const _Float16* __restrict__ Vf,   // frag-major
                 const int* __restrict__ adj,       // [N][N]
                 float* __restrict__ OpartT,        // [JS][FOUT][N]
                 float* __restrict__ mpart,         // [JS][N]
                 float* __restrict__ lpart)         // [JS][N]
{
    __shared__ _Float16 KV[2][16384];   // [buf][16 K frags | 16 V frags]

    const int tid  = threadIdx.x;
    const int wave = tid >> 6;
    const int lane = tid & 63;
    const int lo16 = lane & 15;
    const int quad = lane >> 4;
    const int bid  = blockIdx.x;
    const int js   = bid & (JS - 1);      // XCD affinity
    const int ib   = bid / JS;
    const int i0   = ib * 128;
    const int iw   = i0 + wave * 32;
    const int jbeg = js * (N / JS);
    const int NIT  = (N / JS) / BN;

    // Q as B-operand fragments for 2 i-subtiles
    half8 q[2][4];
#pragma unroll
    for (int isub = 0; isub < 2; isub++)
#pragma unroll
        for (int kc = 0; kc < 4; kc++)
            q[isub][kc] = *(const half8*)&Hq[(size_t)(iw + isub * 16 + lo16) * FOUT + kc * 32 + quad * 8];

    floatx4 O[8][2];
#pragma unroll
    for (int nt = 0; nt < 8; nt++)
#pragma unroll
        for (int s = 0; s < 2; s++) O[nt][s] = (floatx4){0.f, 0.f, 0.f, 0.f};
    float m_s[2] = {-1e12f, -1e12f}, l_s[2] = {0.f, 0.f};

    // prologue: adj window 0 loads (one iteration of slack before ballot)
    int av[32];
    {
        const int* ap = adj + (size_t)iw * N + jbeg + lane;
#pragma unroll
        for (int x = 0; x < 32; x++) av[x] = ap[(size_t)x * N];
    }

    // prologue: stage KV tile 0 into buf 0
    {
        const int jb0 = jbeg >> 6;
        const _Float16* gk = Kf + (size_t)jb0 * 8192;
        const _Float16* gv = Vf + (size_t)jb0 * 8192;
#pragma unroll
        for (int r = 0; r < 4; r++) {
            int off = (r * 256 + tid) * 8;
            *(half8*)&KV[0][off]        = *(const half8*)&gk[off];
            *(half8*)&KV[0][8192 + off] = *(const half8*)&gv[off];
        }
        __syncthreads();
    }

    int cur = 0;
    for (int it = 0; it < NIT; it++) {
        const int j0 = jbeg + it * BN;

        // ---- 1) ballot the adj window loaded one iteration ago (arrived) ----
        unsigned long long mw0 = 0, mw1 = 0;
#pragma unroll
        for (int x = 0; x < 16; x++) {
            unsigned long long b0 = __ballot(av[x] != 0);
            unsigned long long b1 = __ballot(av[x + 16] != 0);
            bool sel = (lo16 == x);
            mw0 = sel ? b0 : mw0;
            mw1 = sel ? b1 : mw1;
        }
        unsigned long long mw[2] = {mw0, mw1};

        // ---- 2) issue adj loads for the NEXT window (in flight all iter) ----
        if (it + 1 < NIT) {
            const int* ap = adj + (size_t)iw * N + (j0 + BN) + lane;
#pragma unroll
            for (int x = 0; x < 32; x++) av[x] = ap[(size_t)x * N];
        }

        // ---- 3) prefetch next KV tile into regs ----
        half8 st[8];
        if (it + 1 < NIT) {
            const int jbn = (j0 + BN) >> 6;
            const _Float16* gk = Kf + (size_t)jbn * 8192;
            const _Float16* gv = Vf + (size_t)jbn * 8192;
#pragma unroll
            for (int r = 0; r < 4; r++) {
                int off = (r * 256 + tid) * 8;
                st[r]     = *(const half8*)&gk[off];
                st[r + 4] = *(const half8*)&gv[off];
            }
        }

        const _Float16* kb = &KV[cur][0];
        const _Float16* vb = &KV[cur][8192];

        // ---- 4) S^T = K Q^T : C-row = j (sigma-permuted), C-col = i ----
        floatx4 S[2][2][2];   // [c][ntj][isub]
#pragma unroll
        for (int c = 0; c < 2; c++)
#pragma unroll
            for (int ntj = 0; ntj < 2; ntj++) {
                S[c][ntj][0] = (floatx4){0.f, 0.f, 0.f, 0.f};
                S[c][ntj][1] = (floatx4){0.f, 0.f, 0.f, 0.f};
#pragma unroll
                for (int kc = 0; kc < 4; kc++) {
                    half8 kf = *(const half8*)&kb[(((c * 2 + ntj) * 4 + kc) * 64 + lane) * 8];
                    S[c][ntj][0] = __builtin_amdgcn_mfma_f32_16x16x32_f16(kf, q[0][kc], S[c][ntj][0], 0, 0, 0);
                    S[c][ntj][1] = __builtin_amdgcn_mfma_f32_16x16x32_f16(kf, q[1][kc], S[c][ntj][1], 0, 0, 0);
                }
            }

        // ---- 5) unmasked running max per i (LeakyReLU inline) ----
        float alpha[2];
#pragma unroll
        for (int s = 0; s < 2; s++) {
            float mx = -1e12f;
#pragma unroll
            for (int c = 0; c < 2; c++)
#pragma unroll
                for (int ntj = 0; ntj < 2; ntj++)
#pragma unroll
                    for (int r = 0; r < 4; r++) {
                        float e = S[c][ntj][s][r];
                        e = e > 0.f ? e : 0.2f * e;
                        mx = fmaxf(mx, e);
                    }
            mx = fmaxf(mx, __shfl_xor(mx, 16));
            mx = fmaxf(mx, __shfl_xor(mx, 32));
            float mn = fmaxf(m_s[s], mx);
            alpha[s] = __expf(m_s[s] - mn);
            m_s[s] = mn;
        }

        // ---- 6) P = mask ? exp(leaky(S) - m) : 0 ; pack into B-fragments ----
        half8 pb[2][2];       // [isub][c], element jj = 4*ntj + r
        float sum[2] = {0.f, 0.f};
#pragma unroll
        for (int s = 0; s < 2; s++) {
            unsigned long long mq = mw[s] >> (quad * 8);
#pragma unroll
            for (int c = 0; c < 2; c++)
#pragma unroll
                for (int ntj = 0; ntj < 2; ntj++)
#pragma unroll
                    for (int r = 0; r < 4; r++) {
                        float e = S[c][ntj][s][r];
                        e = e > 0.f ? e : 0.2f * e;
                        bool bit = (mq >> (c * 32 + ntj * 4 + r)) & 1ull;
                        float p = bit ? __expf(e - m_s[s]) : 0.f;
                        sum[s] += p;
                        pb[s][c][ntj * 4 + r] = (_Float16)p;
                    }
            sum[s] += __shfl_xor(sum[s], 16);
            sum[s] += __shfl_xor(sum[s], 32);
            l_s[s] = l_s[s] * alpha[s] + sum[s];
#pragma unroll
            for (int nt = 0; nt < 8; nt++)
#pragma unroll
                for (int r = 0; r < 4; r++)
                    O[nt][s][r] *= alpha[s];
        }

        // ---- 7) O^T += V^T P^T ----
#pragma unroll
        for (int c = 0; c < 2; c++)
#pragma unroll
            for (int nt = 0; nt < 8; nt++) {
                half8 vf = *(const half8*)&vb[((nt * 2 + c) * 64 + lane) * 8];
                O[nt][0] = __builtin_amdgcn_mfma_f32_16x16x32_f16(vf, pb[0][c], O[nt][0], 0, 0, 0);
                O[nt][1] = __builtin_amdgcn_mfma_f32_16x16x32_f16(vf, pb[1][c], O[nt][1], 0, 0, 0);
            }

        // ---- 8) commit prefetched KV tile; one barrier per iter ----
        if (it + 1 < NIT) {
            const int nxt = cur ^ 1;
#pragma unroll
            for (int r = 0; r < 4; r++) {
                int off = (r * 256 + tid) * 8;
                *(half8*)&KV[nxt][off]        = st[r];
                *(half8*)&KV[nxt][8192 + off] = st[r + 4];
            }
        }
        __syncthreads();
        cur ^= 1;
    }

    // epilogue: O^T[f][i] -> OpartT[js][f][i] (unnormalized) + (m,l)
#pragma unroll
    for (int nt = 0; nt < 8; nt++)
#pragma unroll
        for (int s = 0; s < 2; s++)
#pragma unroll
            for (int r = 0; r < 4; r++) {
                int f = nt * 16 + quad * 4 + r;
                int i = iw + s * 16 + lo16;
                OpartT[((size_t)js * FOUT + f) * N + i] = O[nt][s][r];
            }
    if (quad == 0) {
#pragma unroll
        for (int s = 0; s < 2; s++) {
            mpart[js * N + iw + s * 16 + lo16] = m_s[s];
            lpart[js * N + iw + s * 16 + lo16] = l_s[s];
        }
    }
}

// ---------------------------------------------------------------------------
// Combine: f-major partials -> normalize -> ELU -> out[i][f].
// ---------------------------------------------------------------------------
template<int JS>
__global__ __launch_bounds__(256)
void combine_kernel(const float* __restrict__ OpartT,
                    const float* __restrict__ mpart,
                    const float* __restrict__ lpart,
                    float* __restrict__ out)
{
    int idx = blockIdx.x * 256 + threadIdx.x;   // 128 f x 2048 i-groups
    int f  = idx >> 11;
    int i4 = (idx & 2047) << 2;

    float4 M = {-3e38f, -3e38f, -3e38f, -3e38f};
    float4 m[JS];
#pragma unroll
    for (int s = 0; s < JS; s++) {
        m[s] = *(const float4*)&mpart[s * N + i4];
        M.x = fmaxf(M.x, m[s].x); M.y = fmaxf(M.y, m[s].y);
        M.z = fmaxf(M.z, m[s].z); M.w = fmaxf(M.w, m[s].w);
    }
    float4 L = {0.f, 0.f, 0.f, 0.f};
    float4 w[JS];
#pragma unroll
    for (int s = 0; s < JS; s++) {
        float4 l = *(const float4*)&lpart[s * N + i4];
        w[s].x = __expf(m[s].x - M.x); w[s].y = __expf(m[s].y - M.y);
        w[s].z = __expf(m[s].z - M.z); w[s].w = __expf(m[s].w - M.w);
        L.x += l.x * w[s].x; L.y += l.y * w[s].y;
        L.z += l.z * w[s].z; L.w += l.w * w[s].w;
    }
    float4 o = {0.f, 0.f, 0.f, 0.f};
#pragma unroll
    for (int s = 0; s < JS; s++) {
        float4 v = *(const float4*)&OpartT[((size_t)s * FOUT + f) * N + i4];
        o.x += w[s].x * v.x; o.y += w[s].y * v.y;
        o.z += w[s].z * v.z; o.w += w[s].w * v.w;
    }
    float r0 = o.x / L.x, r1 = o.y / L.y, r2 = o.z / L.z, r3 = o.w / L.w;
    out[(size_t)(i4 + 0) * FOUT + f] = r0 > 0.f ? r0 : __expf(r0) - 1.f;
    out[(size_t)(i4 + 1) * FOUT + f] = r1 > 0.f ? r1 : __expf(r1) - 1.f;
    out[(size_t)(i4 + 2) * FOUT + f] = r2 > 0.f ? r2 : __expf(r2) - 1.f;
    out[(size_t)(i4 + 3) * FOUT + f] = r3 > 0.f ? r3 : __expf(r3) - 1.f;
}

// ---------------------------------------------------------------------------
extern "C" void kernel_launch(void* const* d_in, const int* in_sizes, int n_in,
                              void* d_out, int out_size, void* d_ws, size_t ws_size,
                              hipStream_t stream) {
    const float* inp = (const float*)d_in[0];
    const int*   adj = (const int*)d_in[1];
    const float* W0  = (const float*)d_in[2];
    const float* W1  = (const float*)d_in[3];
    const float* W2  = (const float*)d_in[4];
    float* out = (float*)d_out;

    constexpr int JS = 8;
    char* ws = (char*)d_ws;
    _Float16* H    = (_Float16*)(ws);                          // 2 MB
    _Float16* H2   = (_Float16*)(ws + (2u << 20));             // 2 MB
    _Float16* H3T  = (_Float16*)(ws + (4u << 20));             // 2 MB
    _Float16* Wf   = (_Float16*)(ws + (6u << 20));             // 192 KB
    _Float16* Kf   = (_Float16*)(ws + (7u << 20));             // 2 MB
    _Float16* Vf   = (_Float16*)(ws + (9u << 20));             // 2 MB
    float* OpartT  = (float*)(ws + (11u << 20));               // 32 MB
    float* mpart   = (float*)(ws + (43u << 20));               // 256 KB
    float* lpart   = (float*)(ws + (43u << 20) + (size_t)JS * N * sizeof(float));

    wprep_kernel<<<48, 256, 0, stream>>>(W0, W1, W2, Wf);
    gemm3_kernel<<<dim3(N / 64, 2, 3), 256, 0, stream>>>(inp, Wf, H, H2, H3T);
    repackK_kernel<<<512, 256, 0, stream>>>(H2, Kf);
    repackV_kernel<<<512, 256, 0, stream>>>(H3T, Vf);
    attn_kernel<JS><<<(N / 128) * JS, 256, 0, stream>>>(H, Kf, Vf, adj, OpartT, mpart, lpart);
    combine_kernel<JS><<<(FOUT * (N / 4)) / 256, 256, 0, stream>>>(OpartT, mpart, lpart, out);
}